// Round 23
// baseline (167.723 us; speedup 1.0000x reference)
//
#include <hip/hip_runtime.h>
#include <hip/hip_bf16.h>

typedef float f32x4 __attribute__((ext_vector_type(4)));
typedef float f32x16 __attribute__((ext_vector_type(16)));
typedef unsigned int u32;
typedef u32 u32x2 __attribute__((ext_vector_type(2)));
typedef u32 u32x4 __attribute__((ext_vector_type(4)));
typedef short bf16x8 __attribute__((ext_vector_type(8)));

#define SD 8192      // S*D
#define NROWS 8192   // B*N
#define NN 4096      // N
#define DD 2048      // D
#define DTP 4104     // padded u32 row stride for dT (+8 u32 -> A-frag reads conflict-free)

__device__ __forceinline__ u32 bfr(float f) {   // f32 -> bf16 bits, RNE (K0 only)
    u32 u = __float_as_uint(f);
    return (u + 0x7fffu + ((u >> 16) & 1u)) >> 16;
}
__device__ __forceinline__ float blo(u32 u) { return __uint_as_float(u << 16); }
__device__ __forceinline__ float bhi(u32 u) { return __uint_as_float(u & 0xffff0000u); }

// K0: weights in MFMA B-fragment order (R14/R17-verified):
//   Wfrag[(stg*64+lane)*8+e] = W[k=lane&31][j=stg*16+((lane>>5)&1)*8+e]
__global__ void k0_prep(const float* __restrict__ gamma,
                        const float* __restrict__ daf,
                        const float* __restrict__ dbf,
                        unsigned short* __restrict__ Wfrag) {
    int idx = blockIdx.x * 256 + threadIdx.x;
    if (idx >= 32 * SD) return;
    const int e    = idx & 7;
    const int lane = (idx >> 3) & 63;
    const int stg  = idx >> 9;          // 0..511
    const int outk = lane & 31;
    const int j    = stg * 16 + ((lane >> 5) & 1) * 8 + e;
    unsigned short v = 0;
    if (outk < 24) {
        float g = gamma[j] + 1.0f;
        float w = (outk < 20) ? daf[j * 20 + outk] : dbf[j * 4 + (outk - 20)];
        v = (unsigned short)bfr(w * g);
    }
    Wfrag[idx] = v;
}

// KF: fused, K-TILED P1||P2 pipeline, 3-DEEP data prefetch (R20 + depth 3 +
// pc-reduction folded into P3, saving one barrier/phase in the serial tail).
// Block = 4 rows, 512 threads (8 waves), 2 blocks/CU (LDS ~70 KiB).
// j split into 8 tiles of 1024; named buffers vA/vB/vC, tile t uses buffer
// t%3 (static: A,B,C,A,B,C,A,B — 2x 3-tile rolled loop + 2-tile epilogue).
// Per tile t:
//   [consume vX: ssq+cvt+ds_write dT(t)] [B(t) L2 loads] [vX <- tile t+3 HBM]
//   [s_waitcnt lgkmcnt(0) ONLY + raw s_barrier]   <- HBM loads stay in flight
//   [8 x (ds_read A + MFMA)]
// Consume-to-issue distance = 3 tiles (> HBM latency). B before refill so
// in-order vmcnt never drains the younger HBM loads (R15).
// P3: wave 0 sums the 8 pc partials inline (no separate red phase) -> sinkhorn.
// P4 (mix from dT LDS, nt stores): verbatim R14 (verified).
__global__ __launch_bounds__(512) void kf(const float* __restrict__ res,
                                          const unsigned short* __restrict__ Wfrag,
                                          const float* __restrict__ sa,
                                          const float* __restrict__ sb,
                                          const float* __restrict__ pbs,
                                          const float* __restrict__ rsc,
                                          const float* __restrict__ hps,
                                          float* __restrict__ out) {
    __shared__ u32 dTp[4][DTP];        // packed bf16x2; 65.7 KiB
    __shared__ float pc[8][4][32];     // per-wave partial C
    __shared__ float ssqw[8];
    __shared__ float coefS[4][16];

    const int tid  = threadIdx.x;
    const int wv   = tid >> 6;
    const int lane = tid & 63;
    const int row0 = blockIdx.x * 4;
    const int b    = row0 >> 12;
    const int n0   = row0 & (NN - 1);
    const int r    = tid >> 7;          // staging/mix row 0..3
    const int rem  = tid & 127;

    // ---------- P1||P2: K-tiled pipelined stage + MFMA, 3-deep prefetch ----------
    {
        const float* rowbase = res + ((size_t)(b * 4) * NN + (n0 + r)) * DD;
        const u32* abase = &dTp[lane & 3][wv * 64 + (lane >> 5) * 4];
        const unsigned short* wb0 = Wfrag + (size_t)lane * 8;

        f32x16 acc;
#pragma unroll
        for (int i = 0; i < 16; ++i) acc[i] = 0.f;
        float ssq = 0.f;

        f32x4 vA0, vA1, vB0, vB1, vC0, vC1;

#define LDV(V0, V1, T)                                                        \
        do {                                                                  \
            const int j0_ = (T) * 1024 + rem * 8;                             \
            const int s_ = j0_ >> 11, d_ = j0_ & 2047;                        \
            const float* p_ = rowbase + (size_t)s_ * NN * DD + d_;            \
            V0 = *(const f32x4*)(p_);                                         \
            V1 = *(const f32x4*)(p_ + 4);                                     \
        } while (0)

#define CONSUME(V0, V1, T)                                                    \
        do {                                                                  \
            ssq += V0.x * V0.x + V0.y * V0.y + V0.z * V0.z + V0.w * V0.w;     \
            ssq += V1.x * V1.x + V1.y * V1.y + V1.z * V1.z + V1.w * V1.w;     \
            u32 c0_, c1_, c2_, c3_;                                           \
            asm("v_cvt_pk_bf16_f32 %0, %1, %2" : "=v"(c0_) : "v"(V0.x), "v"(V0.y)); \
            asm("v_cvt_pk_bf16_f32 %0, %1, %2" : "=v"(c1_) : "v"(V0.z), "v"(V0.w)); \
            asm("v_cvt_pk_bf16_f32 %0, %1, %2" : "=v"(c2_) : "v"(V1.x), "v"(V1.y)); \
            asm("v_cvt_pk_bf16_f32 %0, %1, %2" : "=v"(c3_) : "v"(V1.z), "v"(V1.w)); \
            *(u32x4*)&dTp[r][(T) * 512 + rem * 4] = (u32x4){c0_, c1_, c2_, c3_}; \
        } while (0)

#define BLOAD(BU, T)                                                          \
        do {                                                                  \
            _Pragma("unroll")                                                 \
            for (int s8_ = 0; s8_ < 8; ++s8_)                                 \
                BU[s8_] = *(const u32x4*)(wb0 + (size_t)(((T) * 64 + wv * 8 + s8_) * 64) * 8); \
        } while (0)

#define MMT(BU, T)                                                            \
        do {                                                                  \
            asm volatile("s_waitcnt lgkmcnt(0)" ::: "memory");                \
            __builtin_amdgcn_sched_barrier(0);                                \
            __builtin_amdgcn_s_barrier();                                     \
            _Pragma("unroll")                                                 \
            for (int s8_ = 0; s8_ < 8; ++s8_) {                               \
                const u32x4 au_ = *(const u32x4*)(abase + (T) * 512 + s8_ * 8); \
                acc = __builtin_amdgcn_mfma_f32_32x32x16_bf16(                \
                    __builtin_bit_cast(bf16x8, au_),                          \
                    __builtin_bit_cast(bf16x8, BU[s8_]), acc, 0, 0, 0);       \
            }                                                                 \
            __builtin_amdgcn_sched_barrier(0);                                \
        } while (0)

        LDV(vA0, vA1, 0);
        LDV(vB0, vB1, 1);
        LDV(vC0, vC1, 2);
#pragma unroll 1
        for (int tp = 0; tp < 2; ++tp) {
            const int t0 = tp * 3, t1 = t0 + 1, t2 = t0 + 2;
            // tile t0: consume vA, refill vA <- t0+3 (3 and 6, always valid)
            CONSUME(vA0, vA1, t0);
            {
                u32x4 bu[8];
                BLOAD(bu, t0);
                LDV(vA0, vA1, t0 + 3);
                MMT(bu, t0);
            }
            // tile t1: consume vB, refill vB <- t1+3 (4 and 7, always valid)
            CONSUME(vB0, vB1, t1);
            {
                u32x4 bu[8];
                BLOAD(bu, t1);
                LDV(vB0, vB1, t1 + 3);
                MMT(bu, t1);
            }
            // tile t2: consume vC, refill vC <- t2+3 (5 valid; 8 skipped)
            CONSUME(vC0, vC1, t2);
            {
                u32x4 bu[8];
                BLOAD(bu, t2);
                if (tp == 0) LDV(vC0, vC1, 5);
                MMT(bu, t2);
            }
        }
        // epilogue tiles 6 (vA) and 7 (vB)
        CONSUME(vA0, vA1, 6);
        {
            u32x4 bu[8];
            BLOAD(bu, 6);
            MMT(bu, 6);
        }
        CONSUME(vB0, vB1, 7);
        {
            u32x4 bu[8];
            BLOAD(bu, 7);
            MMT(bu, 7);
        }
#undef LDV
#undef CONSUME
#undef BLOAD
#undef MMT

        // ssq: wave covers a single row -> butterfly, one slot per wave
        ssq += __shfl_xor(ssq, 1);  ssq += __shfl_xor(ssq, 2);
        ssq += __shfl_xor(ssq, 4);  ssq += __shfl_xor(ssq, 8);
        ssq += __shfl_xor(ssq, 16); ssq += __shfl_xor(ssq, 32);
        if (lane == 0) ssqw[wv] = ssq;
        if (lane < 32) {
#pragma unroll
            for (int gg = 0; gg < 4; ++gg) pc[wv][gg][lane] = acc[gg];
        }
    }
    __syncthreads();

    // ---------- P3: sinkhorn + coeff (wave 0; 4 rows x 16 lanes);
    // pc partials summed inline (no separate reduction phase/barrier) ----------
    if (wv == 0) {
        const int rr = lane >> 4, l = lane & 15, s = l >> 2, t = l & 3;
        const float ssqr  = ssqw[2 * rr] + ssqw[2 * rr + 1];
        const float scale = 90.50966799187809f / fmaxf(sqrtf(ssqr), 1e-12f);
        float P = 0.f, P0 = 0.f, Pb = 0.f;
#pragma unroll
        for (int w = 0; w < 8; ++w) {
            P  += pc[w][rr][s * 5 + t + 1];
            P0 += pc[w][rr][s * 5];
            Pb += pc[w][rr][20 + t];
        }
        float la = scale * P * rsc[0] + sa[s * 5 + t + 1];
        const float a0 = scale * P0 * pbs[0] + sa[s * 5];
        const float ap = 1.f / (1.f + __expf(-a0));
        const float bt = 2.f / (1.f + __expf(-(scale * Pb * hps[0] + sb[t])));
#pragma unroll
        for (int it = 0; it < 20; ++it) {
            float m = fmaxf(la, __shfl_xor(la, 4));
            m = fmaxf(m, __shfl_xor(m, 8));
            float e = __expf(la - m);
            e += __shfl_xor(e, 4);
            e += __shfl_xor(e, 8);
            la -= m + __logf(e);
            m = fmaxf(la, __shfl_xor(la, 1));
            m = fmaxf(m, __shfl_xor(m, 2));
            e = __expf(la - m);
            e += __shfl_xor(e, 1);
            e += __shfl_xor(e, 2);
            la -= m + __logf(e);
        }
        coefS[rr][t * 4 + s] = ap * bt + __expf(la);
    }
    __syncthreads();

    // ---------- P4: mix + store (rolled, packed FMA) ----------
    float cf[16];
#pragma unroll
    for (int i = 0; i < 16; ++i) cf[i] = coefS[r][i];
    float* ob = out + ((size_t)(b * 4) * NN + (n0 + r)) * DD;
#pragma unroll 1
    for (int qq = 0; qq < 4; ++qq) {
        const int dp = (rem + 128 * qq) * 2;    // u32 index within s-plane
        f32x4 dv4[4];
#pragma unroll
        for (int s = 0; s < 4; ++s) {
            u32x2 u = *(const u32x2*)&dTp[r][s * 1024 + dp];
            dv4[s] = (f32x4){blo(u[0]), bhi(u[0]), blo(u[1]), bhi(u[1])};
        }
#pragma unroll
        for (int t = 0; t < 4; ++t) {
            f32x4 o = cf[t * 4 + 0] * dv4[0];
            o += cf[t * 4 + 1] * dv4[1];
            o += cf[t * 4 + 2] * dv4[2];
            o += cf[t * 4 + 3] * dv4[3];
            __builtin_nontemporal_store(o, (f32x4*)(ob + (size_t)t * NN * DD + dp * 2));
        }
    }
}

extern "C" void kernel_launch(void* const* d_in, const int* in_sizes, int n_in,
                              void* d_out, int out_size, void* d_ws, size_t ws_size,
                              hipStream_t stream) {
    const float* residuals = (const float*)d_in[0];
    const float* gamma     = (const float*)d_in[1];
    const float* daf       = (const float*)d_in[2];
    const float* sa        = (const float*)d_in[3];
    const float* pbs       = (const float*)d_in[4];
    const float* rsc       = (const float*)d_in[5];
    const float* dbf       = (const float*)d_in[6];
    const float* sb        = (const float*)d_in[7];
    const float* hps       = (const float*)d_in[8];
    float* out = (float*)d_out;

    unsigned short* Wfrag = (unsigned short*)d_ws;  // 512 KiB, fragment order

    k0_prep<<<1024, 256, 0, stream>>>(gamma, daf, dbf, Wfrag);
    kf<<<NROWS / 4, 512, 0, stream>>>(residuals, Wfrag, sa, sb, pbs, rsc, hps, out);
}

// Round 24
// 121.262 us; speedup vs baseline: 1.3831x; 1.3831x over previous
//
#include <hip/hip_runtime.h>
#include <hip/hip_bf16.h>

typedef float f32x4 __attribute__((ext_vector_type(4)));
typedef float f32x16 __attribute__((ext_vector_type(16)));
typedef unsigned int u32;
typedef u32 u32x2 __attribute__((ext_vector_type(2)));
typedef u32 u32x4 __attribute__((ext_vector_type(4)));
typedef short bf16x8 __attribute__((ext_vector_type(8)));

#define SD 8192      // S*D
#define NROWS 8192   // B*N
#define NN 4096      // N
#define DD 2048      // D
#define DTP 4104     // padded u32 row stride for dT (+8 u32 -> A-frag reads conflict-free)

__device__ __forceinline__ u32 bfr(float f) {   // f32 -> bf16 bits, RNE (K0 only)
    u32 u = __float_as_uint(f);
    return (u + 0x7fffu + ((u >> 16) & 1u)) >> 16;
}
__device__ __forceinline__ float blo(u32 u) { return __uint_as_float(u << 16); }
__device__ __forceinline__ float bhi(u32 u) { return __uint_as_float(u & 0xffff0000u); }

// K0: weights in MFMA B-fragment order (R14/R17-verified):
//   Wfrag[(stg*64+lane)*8+e] = W[k=lane&31][j=stg*16+((lane>>5)&1)*8+e]
__global__ void k0_prep(const float* __restrict__ gamma,
                        const float* __restrict__ daf,
                        const float* __restrict__ dbf,
                        unsigned short* __restrict__ Wfrag) {
    int idx = blockIdx.x * 256 + threadIdx.x;
    if (idx >= 32 * SD) return;
    const int e    = idx & 7;
    const int lane = (idx >> 3) & 63;
    const int stg  = idx >> 9;          // 0..511
    const int outk = lane & 31;
    const int j    = stg * 16 + ((lane >> 5) & 1) * 8 + e;
    unsigned short v = 0;
    if (outk < 24) {
        float g = gamma[j] + 1.0f;
        float w = (outk < 20) ? daf[j * 20 + outk] : dbf[j * 4 + (outk - 20)];
        v = (unsigned short)bfr(w * g);
    }
    Wfrag[idx] = v;
}

// KF: fused, K-TILED P1||P2 pipeline with 2-DEEP data prefetch — the R20
// family optimum (122 us measured; depth-1/3, tile-2048, merged pipelines,
// 2-row blocks, and kernel splits ALL regressed around this configuration).
// Block = 4 rows, 512 threads (8 waves), 2 blocks/CU (LDS ~70 KiB).
// j split into 8 tiles of 1024, processed as 4 even/odd pairs (named vA/vB
// buffers, rule-#20-safe). Per tile t:
//   [consume vX: ssq+cvt+ds_write dT(t)] [B(t) L2 loads] [vX <- tile t+2 HBM]
//   [s_waitcnt lgkmcnt(0) ONLY + raw s_barrier]   <- HBM loads stay in flight
//   [8 x (ds_read A + MFMA)]                      <- vmcnt keeps refill alive
// Consume-to-issue distance = 2 tiles (>= HBM latency). B before refill so
// in-order vmcnt never drains the younger HBM loads (R15).
// P3 (sinkhorn) + P4 (mix from dT LDS, nt stores): verbatim R14 (verified).
__global__ __launch_bounds__(512) void kf(const float* __restrict__ res,
                                          const unsigned short* __restrict__ Wfrag,
                                          const float* __restrict__ sa,
                                          const float* __restrict__ sb,
                                          const float* __restrict__ pbs,
                                          const float* __restrict__ rsc,
                                          const float* __restrict__ hps,
                                          float* __restrict__ out) {
    __shared__ u32 dTp[4][DTP];        // packed bf16x2; 65.7 KiB
    __shared__ float pc[8][4][32];     // per-wave partial C
    __shared__ float red[4][32];
    __shared__ float ssqw[8];
    __shared__ float coefS[4][16];

    const int tid  = threadIdx.x;
    const int wv   = tid >> 6;
    const int lane = tid & 63;
    const int row0 = blockIdx.x * 4;
    const int b    = row0 >> 12;
    const int n0   = row0 & (NN - 1);
    const int r    = tid >> 7;          // staging/mix row 0..3
    const int rem  = tid & 127;

    // ---------- P1||P2: K-tiled pipelined stage + MFMA, 2-deep prefetch ----------
    {
        const float* rowbase = res + ((size_t)(b * 4) * NN + (n0 + r)) * DD;
        const u32* abase = &dTp[lane & 3][wv * 64 + (lane >> 5) * 4];
        const unsigned short* wb0 = Wfrag + (size_t)lane * 8;

        f32x16 acc;
#pragma unroll
        for (int i = 0; i < 16; ++i) acc[i] = 0.f;
        float ssq = 0.f;

        f32x4 vA0, vA1, vB0, vB1;

#define LDV(V0, V1, T)                                                        \
        do {                                                                  \
            const int j0_ = (T) * 1024 + rem * 8;                             \
            const int s_ = j0_ >> 11, d_ = j0_ & 2047;                        \
            const float* p_ = rowbase + (size_t)s_ * NN * DD + d_;            \
            V0 = *(const f32x4*)(p_);                                         \
            V1 = *(const f32x4*)(p_ + 4);                                     \
        } while (0)

#define CONSUME(V0, V1, T)                                                    \
        do {                                                                  \
            ssq += V0.x * V0.x + V0.y * V0.y + V0.z * V0.z + V0.w * V0.w;     \
            ssq += V1.x * V1.x + V1.y * V1.y + V1.z * V1.z + V1.w * V1.w;     \
            u32 c0_, c1_, c2_, c3_;                                           \
            asm("v_cvt_pk_bf16_f32 %0, %1, %2" : "=v"(c0_) : "v"(V0.x), "v"(V0.y)); \
            asm("v_cvt_pk_bf16_f32 %0, %1, %2" : "=v"(c1_) : "v"(V0.z), "v"(V0.w)); \
            asm("v_cvt_pk_bf16_f32 %0, %1, %2" : "=v"(c2_) : "v"(V1.x), "v"(V1.y)); \
            asm("v_cvt_pk_bf16_f32 %0, %1, %2" : "=v"(c3_) : "v"(V1.z), "v"(V1.w)); \
            *(u32x4*)&dTp[r][(T) * 512 + rem * 4] = (u32x4){c0_, c1_, c2_, c3_}; \
        } while (0)

#define BLOAD(BU, T)                                                          \
        do {                                                                  \
            _Pragma("unroll")                                                 \
            for (int s8_ = 0; s8_ < 8; ++s8_)                                 \
                BU[s8_] = *(const u32x4*)(wb0 + (size_t)(((T) * 64 + wv * 8 + s8_) * 64) * 8); \
        } while (0)

#define MMT(BU, T)                                                            \
        do {                                                                  \
            asm volatile("s_waitcnt lgkmcnt(0)" ::: "memory");                \
            __builtin_amdgcn_sched_barrier(0);                                \
            __builtin_amdgcn_s_barrier();                                     \
            _Pragma("unroll")                                                 \
            for (int s8_ = 0; s8_ < 8; ++s8_) {                               \
                const u32x4 au_ = *(const u32x4*)(abase + (T) * 512 + s8_ * 8); \
                acc = __builtin_amdgcn_mfma_f32_32x32x16_bf16(                \
                    __builtin_bit_cast(bf16x8, au_),                          \
                    __builtin_bit_cast(bf16x8, BU[s8_]), acc, 0, 0, 0);       \
            }                                                                 \
            __builtin_amdgcn_sched_barrier(0);                                \
        } while (0)

        LDV(vA0, vA1, 0);
        LDV(vB0, vB1, 1);
#pragma unroll 1
        for (int tp = 0; tp < 4; ++tp) {
            const int t0 = tp * 2, t1 = t0 + 1;
            // even tile: consume vA, refill vA <- t0+2
            CONSUME(vA0, vA1, t0);
            u32x4 bu0[8];
            BLOAD(bu0, t0);
            if (t0 < 6) LDV(vA0, vA1, t0 + 2);
            MMT(bu0, t0);
            // odd tile: consume vB, refill vB <- t1+2
            CONSUME(vB0, vB1, t1);
            u32x4 bu1[8];
            BLOAD(bu1, t1);
            if (t1 < 7) LDV(vB0, vB1, t1 + 2);
            MMT(bu1, t1);
        }
#undef LDV
#undef CONSUME
#undef BLOAD
#undef MMT

        // ssq: wave covers a single row -> butterfly, one slot per wave
        ssq += __shfl_xor(ssq, 1);  ssq += __shfl_xor(ssq, 2);
        ssq += __shfl_xor(ssq, 4);  ssq += __shfl_xor(ssq, 8);
        ssq += __shfl_xor(ssq, 16); ssq += __shfl_xor(ssq, 32);
        if (lane == 0) ssqw[wv] = ssq;
        if (lane < 32) {
#pragma unroll
            for (int gg = 0; gg < 4; ++gg) pc[wv][gg][lane] = acc[gg];
        }
    }
    __syncthreads();
    if (tid < 128) {
        const int rr = tid >> 5, c = tid & 31;
        float s = 0.f;
#pragma unroll
        for (int w = 0; w < 8; ++w) s += pc[w][rr][c];
        red[rr][c] = s;
    }
    __syncthreads();

    // ---------- P3: sinkhorn + coeff (wave 0; 4 rows x 16 lanes) ----------
    if (wv == 0) {
        const int rr = lane >> 4, l = lane & 15, s = l >> 2, t = l & 3;
        const float ssqr  = ssqw[2 * rr] + ssqw[2 * rr + 1];
        const float scale = 90.50966799187809f / fmaxf(sqrtf(ssqr), 1e-12f);
        const float P  = red[rr][s * 5 + t + 1];
        const float P0 = red[rr][s * 5];
        const float Pb = red[rr][20 + t];
        float la = scale * P * rsc[0] + sa[s * 5 + t + 1];
        const float a0 = scale * P0 * pbs[0] + sa[s * 5];
        const float ap = 1.f / (1.f + __expf(-a0));
        const float bt = 2.f / (1.f + __expf(-(scale * Pb * hps[0] + sb[t])));
#pragma unroll
        for (int it = 0; it < 20; ++it) {
            float m = fmaxf(la, __shfl_xor(la, 4));
            m = fmaxf(m, __shfl_xor(m, 8));
            float e = __expf(la - m);
            e += __shfl_xor(e, 4);
            e += __shfl_xor(e, 8);
            la -= m + __logf(e);
            m = fmaxf(la, __shfl_xor(la, 1));
            m = fmaxf(m, __shfl_xor(m, 2));
            e = __expf(la - m);
            e += __shfl_xor(e, 1);
            e += __shfl_xor(e, 2);
            la -= m + __logf(e);
        }
        coefS[rr][t * 4 + s] = ap * bt + __expf(la);
    }
    __syncthreads();

    // ---------- P4: mix + store (rolled, packed FMA) ----------
    float cf[16];
#pragma unroll
    for (int i = 0; i < 16; ++i) cf[i] = coefS[r][i];
    float* ob = out + ((size_t)(b * 4) * NN + (n0 + r)) * DD;
#pragma unroll 1
    for (int qq = 0; qq < 4; ++qq) {
        const int dp = (rem + 128 * qq) * 2;    // u32 index within s-plane
        f32x4 dv4[4];
#pragma unroll
        for (int s = 0; s < 4; ++s) {
            u32x2 u = *(const u32x2*)&dTp[r][s * 1024 + dp];
            dv4[s] = (f32x4){blo(u[0]), bhi(u[0]), blo(u[1]), bhi(u[1])};
        }
#pragma unroll
        for (int t = 0; t < 4; ++t) {
            f32x4 o = cf[t * 4 + 0] * dv4[0];
            o += cf[t * 4 + 1] * dv4[1];
            o += cf[t * 4 + 2] * dv4[2];
            o += cf[t * 4 + 3] * dv4[3];
            __builtin_nontemporal_store(o, (f32x4*)(ob + (size_t)t * NN * DD + dp * 2));
        }
    }
}

extern "C" void kernel_launch(void* const* d_in, const int* in_sizes, int n_in,
                              void* d_out, int out_size, void* d_ws, size_t ws_size,
                              hipStream_t stream) {
    const float* residuals = (const float*)d_in[0];
    const float* gamma     = (const float*)d_in[1];
    const float* daf       = (const float*)d_in[2];
    const float* sa        = (const float*)d_in[3];
    const float* pbs       = (const float*)d_in[4];
    const float* rsc       = (const float*)d_in[5];
    const float* dbf       = (const float*)d_in[6];
    const float* sb        = (const float*)d_in[7];
    const float* hps       = (const float*)d_in[8];
    float* out = (float*)d_out;

    unsigned short* Wfrag = (unsigned short*)d_ws;  // 512 KiB, fragment order

    k0_prep<<<1024, 256, 0, stream>>>(gamma, daf, dbf, Wfrag);
    kf<<<NROWS / 4, 512, 0, stream>>>(residuals, Wfrag, sa, sb, pbs, rsc, hps, out);
}